// Round 1
// baseline (37.736 us; speedup 1.0000x reference)
//
#include <hip/hip_runtime.h>

#define NF 39
#define NP 741   // 39*38/2

struct PairLUT { unsigned short rc[NP]; };

constexpr PairLUT make_lut() {
    PairLUT L{};
    int p = 0;
    for (int i = 0; i < NF; ++i)
        for (int j = i + 1; j < NF; ++j) {
            L.rc[p] = (unsigned short)((i << 8) | j);
            ++p;
        }
    return L;
}

__constant__ PairLUT LUT = make_lut();

__global__ __launch_bounds__(256) void opn_kernel(const float* __restrict__ x,
                                                  float* __restrict__ out) {
    const int b   = blockIdx.x;
    const int tid = threadIdx.x;
    __shared__ float s[NF + 1];

    const int g = tid >> 4;   // 16 groups of 16 lanes each
    const int l = tid & 15;

    const float* xb = x + (size_t)b * (NF * 64);

    // Each 16-lane group sums one field (64 floats) via float4 loads.
    // A full wave (4 groups) reads a contiguous 1 KiB slab -> ideal coalescing.
    #pragma unroll
    for (int base = 0; base < NF; base += 16) {
        const int f = base + g;
        float v = 0.0f;
        if (f < NF) {
            const float4 t = *reinterpret_cast<const float4*>(xb + f * 64 + l * 4);
            v = (t.x + t.y) + (t.z + t.w);
        }
        v += __shfl_xor(v, 1);
        v += __shfl_xor(v, 2);
        v += __shfl_xor(v, 4);
        v += __shfl_xor(v, 8);
        if (f < NF && l == 0) s[f] = v;
    }
    __syncthreads();

    float* ob = out + (size_t)b * NP;
    #pragma unroll
    for (int p = tid; p < NP; p += 256) {
        const unsigned int rc = LUT.rc[p];
        ob[p] = s[rc >> 8] * s[rc & 255u];
    }
}

extern "C" void kernel_launch(void* const* d_in, const int* in_sizes, int n_in,
                              void* d_out, int out_size, void* d_ws, size_t ws_size,
                              hipStream_t stream) {
    const float* x = (const float*)d_in[0];
    float* out = (float*)d_out;
    const int B = in_sizes[0] / (NF * 64);   // 16384
    opn_kernel<<<B, 256, 0, stream>>>(x, out);
}

// Round 2
// 37.233 us; speedup vs baseline: 1.0135x; 1.0135x over previous
//
#include <hip/hip_runtime.h>

#define NF 39
#define NP 741   // 39*38/2
#define N4 624   // float4s per row = 39*64/4

struct PairLUT { unsigned short rc[NP]; };

constexpr PairLUT make_lut() {
    PairLUT L{};
    int p = 0;
    for (int i = 0; i < NF; ++i)
        for (int j = i + 1; j < NF; ++j) {
            L.rc[p] = (unsigned short)((i << 8) | j);
            ++p;
        }
    return L;
}

__constant__ PairLUT LUT = make_lut();

__global__ __launch_bounds__(256) void opn_kernel(const float* __restrict__ x,
                                                  float* __restrict__ out) {
    const int tid = threadIdx.x;
    const int wid = tid >> 6;   // wave id within block, 0..3
    const int l   = tid & 63;   // lane
    const int b   = blockIdx.x * 4 + wid;   // one row per wave

    __shared__ float s[4][NF + 1];

    const float4* xb4 = reinterpret_cast<const float4*>(x) + (size_t)b * N4;

    // 10 independent float4 loads per lane -> high MLP, all in flight at once.
    float v[10];
    #pragma unroll
    for (int r = 0; r < 9; ++r) {
        const float4 t = xb4[r * 64 + l];
        v[r] = (t.x + t.y) + (t.z + t.w);
    }
    {
        float4 t = {0.f, 0.f, 0.f, 0.f};
        if (576 + l < N4) t = xb4[576 + l];     // tail: 48 of 64 lanes
        v[9] = (t.x + t.y) + (t.z + t.w);
    }

    // float4 index i4 = r*64+l belongs to field f = i4/16 = r*4 + l/16.
    // Reduce each 16-lane group (same field) via shfl_xor; one lane stores to LDS.
    #pragma unroll
    for (int r = 0; r < 10; ++r) {
        float vv = v[r];
        vv += __shfl_xor(vv, 1);
        vv += __shfl_xor(vv, 2);
        vv += __shfl_xor(vv, 4);
        vv += __shfl_xor(vv, 8);
        const int f = r * 4 + (l >> 4);
        if ((l & 15) == 0 && f < NF) s[wid][f] = vv;
    }
    // Intra-wave LDS RAW: no __syncthreads needed (same wave, compiler emits
    // the lgkmcnt wait). Waves proceed independently -> no barrier coupling.

    float* ob = out + (size_t)b * NP;
    #pragma unroll
    for (int k = 0; k < 12; ++k) {
        const int p = k * 64 + l;
        if (p < NP) {
            const unsigned int rc = LUT.rc[p];
            // Nontemporal: don't let the 48.6 MB write stream evict the input
            // from L2/L3 (input+output ~= 212 MB < 256 MB Infinity Cache).
            __builtin_nontemporal_store(s[wid][rc >> 8] * s[wid][rc & 255u], ob + p);
        }
    }
}

extern "C" void kernel_launch(void* const* d_in, const int* in_sizes, int n_in,
                              void* d_out, int out_size, void* d_ws, size_t ws_size,
                              hipStream_t stream) {
    const float* x = (const float*)d_in[0];
    float* out = (float*)d_out;
    const int B = in_sizes[0] / (NF * 64);   // 16384
    opn_kernel<<<B / 4, 256, 0, stream>>>(x, out);
}